// Round 24
// baseline (77.766 us; speedup 1.0000x reference)
//
#include <hip/hip_runtime.h>
#include <hip/hip_bf16.h>
#include <math.h>

#define B_N 4096
#define D_N 1024
#define K_N 256
#define NSTEP 32

typedef __attribute__((ext_vector_type(8))) short bf16x8;           // 4 VGPR
typedef __attribute__((ext_vector_type(8))) unsigned short u16x8;   // 4 VGPR
typedef __attribute__((ext_vector_type(4))) float f32x4;            // MFMA C/D

static constexpr float K_EPS = 1e-8f;

static __device__ __forceinline__ unsigned short f32_to_bf16_rne(float f) {
    unsigned x = __builtin_bit_cast(unsigned, f);
    unsigned r = (x + 0x7FFFu + ((x >> 16) & 1u)) >> 16;
    return (unsigned short)r;
}
static __device__ __forceinline__ float bf16_bits_to_f32(unsigned short h) {
    unsigned x = ((unsigned)h) << 16;
    return __builtin_bit_cast(float, x);
}
static __device__ __forceinline__ void cvt8(
    float e0, float e1, float e2, float e3,
    float e4, float e5, float e6, float e7, u16x8& hv, u16x8& lv)
{
    ushort h0=f32_to_bf16_rne(e0), h1=f32_to_bf16_rne(e1),
           h2=f32_to_bf16_rne(e2), h3=f32_to_bf16_rne(e3),
           h4=f32_to_bf16_rne(e4), h5=f32_to_bf16_rne(e5),
           h6=f32_to_bf16_rne(e6), h7=f32_to_bf16_rne(e7);
    hv = (u16x8){h0,h1,h2,h3,h4,h5,h6,h7};
    lv = (u16x8){f32_to_bf16_rne(e0 - bf16_bits_to_f32(h0)),
                 f32_to_bf16_rne(e1 - bf16_bits_to_f32(h1)),
                 f32_to_bf16_rne(e2 - bf16_bits_to_f32(h2)),
                 f32_to_bf16_rne(e3 - bf16_bits_to_f32(h3)),
                 f32_to_bf16_rne(e4 - bf16_bits_to_f32(h4)),
                 f32_to_bf16_rne(e5 - bf16_bits_to_f32(h5)),
                 f32_to_bf16_rne(e6 - bf16_bits_to_f32(h6)),
                 f32_to_bf16_rne(e7 - bf16_bits_to_f32(h7))};
}

// ---------------------------------------------------------------------------
// Kernel 1: centroid normalize + bf16 hi/lo split into PACKED MFMA-fragment
// layout (R12-verified). FULL hi+lo (lo is load-bearing for argmax — R22).
// ---------------------------------------------------------------------------
__global__ __launch_bounds__(256) void kcent_kernel(
    const float* __restrict__ cent,
    ushort* __restrict__ phi, ushort* __restrict__ plo)
{
    int n   = blockIdx.x;
    int tid = threadIdx.x;
    float4 v = reinterpret_cast<const float4*>(cent + (size_t)n * D_N)[tid];
    float s = v.x * v.x + v.y * v.y + v.z * v.z + v.w * v.w;
    #pragma unroll
    for (int o = 32; o > 0; o >>= 1) s += __shfl_down(s, o);
    __shared__ float red[4];
    __shared__ float s_inv;
    if ((tid & 63) == 0) red[tid >> 6] = s;
    __syncthreads();
    if (tid == 0) {
        float t = red[0] + red[1] + red[2] + red[3];
        s_inv = 1.0f / fmaxf(sqrtf(t), K_EPS);
    }
    __syncthreads();
    float inv = s_inv;
    float e[4] = {v.x * inv, v.y * inv, v.z * inv, v.w * inv};
    ushort h4[4], l4[4];
    #pragma unroll
    for (int j = 0; j < 4; ++j) {
        ushort h = f32_to_bf16_rne(e[j]);
        float lo = e[j] - bf16_bits_to_f32(h);
        h4[j] = h;
        l4[j] = f32_to_bf16_rne(lo);
    }
    int nt = n >> 4, lr = n & 15;
    int k8 = tid >> 1, half = tid & 1;
    int t  = k8 >> 2, lg = k8 & 3;
    size_t chunk = (size_t)(nt * 32 + t) * 64 + lg * 16 + lr;
    *reinterpret_cast<ushort4*>(phi + chunk * 8 + half * 4) =
        make_ushort4(h4[0], h4[1], h4[2], h4[3]);
    *reinterpret_cast<ushort4*>(plo + chunk * 8 + half * 4) =
        make_ushort4(l4[0], l4[1], l4[2], l4[3]);
}

// ---------------------------------------------------------------------------
// Kernel 2 (main): R23-exact. 256 blocks x 1024 threads; 3-MFMA split
// product; depth-8 packed-B rotation; epilogue = sims + indices only.
// ---------------------------------------------------------------------------
__global__ __launch_bounds__(1024) void kmain_kernel(
    const float* __restrict__ dp,
    const ushort* __restrict__ phi, const ushort* __restrict__ plo,
    float* __restrict__ out_sims, float* __restrict__ out_dpidx,
    float* __restrict__ out_hnidx, float* __restrict__ out_top1,
    int* __restrict__ ws_dpidx, int* __restrict__ ws_hnidx)
{
    __shared__ ushort AhL[16 * 1024];   // 32 KB (swizzled)
    __shared__ ushort AlL[16 * 1024];   // 32 KB
    __shared__ float  simsL[16 * 256];  // 16 KB
    int tid  = threadIdx.x;
    int lane = tid & 63;
    int w    = tid >> 6;        // wave 0..15
    int lr   = lane & 15;
    int lg   = lane >> 4;
    int brow = blockIdx.x * 16;

    const ushort* bh = phi + (size_t)w * 32 * 512 + (size_t)lane * 8;
    const ushort* bl = plo + (size_t)w * 32 * 512 + (size_t)lane * 8;

    #define LBF(t, H, L)                                                  \
        H = *reinterpret_cast<const bf16x8*>(bh + (size_t)(t) * 512);     \
        L = *reinterpret_cast<const bf16x8*>(bl + (size_t)(t) * 512);

    bf16x8 h0,l0,h1,l1,h2,l2,h3,l3,h4,l4,h5,l5,h6,l6,h7,l7;
    LBF(0,h0,l0) LBF(1,h1,l1) LBF(2,h2,l2) LBF(3,h3,l3)
    LBF(4,h4,l4) LBF(5,h5,l5) LBF(6,h6,l6) LBF(7,h7,l7)

    {
        const float4* r4 = reinterpret_cast<const float4*>(
            dp + (size_t)(brow + w) * D_N);
        float4 a0 = r4[lane*4+0], a1 = r4[lane*4+1],
               a2 = r4[lane*4+2], a3 = r4[lane*4+3];
        float s = a0.x*a0.x + a0.y*a0.y + a0.z*a0.z + a0.w*a0.w
                + a1.x*a1.x + a1.y*a1.y + a1.z*a1.z + a1.w*a1.w
                + a2.x*a2.x + a2.y*a2.y + a2.z*a2.z + a2.w*a2.w
                + a3.x*a3.x + a3.y*a3.y + a3.z*a3.z + a3.w*a3.w;
        #pragma unroll
        for (int o = 1; o < 64; o <<= 1) s += __shfl_xor(s, o);
        float inv = 1.0f / fmaxf(sqrtf(s), K_EPS);
        u16x8 hv, lv;
        cvt8(a0.x*inv, a0.y*inv, a0.z*inv, a0.w*inv,
             a1.x*inv, a1.y*inv, a1.z*inv, a1.w*inv, hv, lv);
        int slot = (lane*2 + 0) ^ (w & 7);
        *reinterpret_cast<u16x8*>(&AhL[w*1024 + slot*8]) = hv;
        *reinterpret_cast<u16x8*>(&AlL[w*1024 + slot*8]) = lv;
        cvt8(a2.x*inv, a2.y*inv, a2.z*inv, a2.w*inv,
             a3.x*inv, a3.y*inv, a3.z*inv, a3.w*inv, hv, lv);
        slot = (lane*2 + 1) ^ (w & 7);
        *reinterpret_cast<u16x8*>(&AhL[w*1024 + slot*8]) = hv;
        *reinterpret_cast<u16x8*>(&AlL[w*1024 + slot*8]) = lv;
    }
    __syncthreads();

    f32x4 acc = {};
    const char* AhC = (const char*)AhL;
    const char* AlC = (const char*)AlL;
    auto step = [&](int t, bf16x8 hb, bf16x8 lb) {
        unsigned ca = (unsigned)((4*t + lg) ^ (lr & 7));
        unsigned ao = (unsigned)lr * 2048u + ca * 16u;
        bf16x8 ah = *reinterpret_cast<const bf16x8*>(AhC + ao);
        bf16x8 al = *reinterpret_cast<const bf16x8*>(AlC + ao);
        acc = __builtin_amdgcn_mfma_f32_16x16x32_bf16(ah, hb, acc, 0, 0, 0);
        acc = __builtin_amdgcn_mfma_f32_16x16x32_bf16(ah, lb, acc, 0, 0, 0);
        acc = __builtin_amdgcn_mfma_f32_16x16x32_bf16(al, hb, acc, 0, 0, 0);
    };
    #pragma unroll 1
    for (int t = 0; t < NSTEP; t += 8) {
        step(t + 0, h0, l0); if (t +  8 < NSTEP) { LBF(t +  8, h0, l0) }
        step(t + 1, h1, l1); if (t +  9 < NSTEP) { LBF(t +  9, h1, l1) }
        step(t + 2, h2, l2); if (t + 10 < NSTEP) { LBF(t + 10, h2, l2) }
        step(t + 3, h3, l3); if (t + 11 < NSTEP) { LBF(t + 11, h3, l3) }
        step(t + 4, h4, l4); if (t + 12 < NSTEP) { LBF(t + 12, h4, l4) }
        step(t + 5, h5, l5); if (t + 13 < NSTEP) { LBF(t + 13, h5, l5) }
        step(t + 6, h6, l6); if (t + 14 < NSTEP) { LBF(t + 14, h6, l6) }
        step(t + 7, h7, l7); if (t + 15 < NSTEP) { LBF(t + 15, h7, l7) }
    }
    #undef LBF

    #pragma unroll
    for (int r = 0; r < 4; ++r)
        simsL[(lg*4 + r) * K_N + w*16 + lr] = acc[r];
    __syncthreads();

    {
        float4 c = *reinterpret_cast<const float4*>(&simsL[w * K_N + lane * 4]);
        int row = brow + w;
        *reinterpret_cast<float4*>(&out_sims[(size_t)row * K_N + lane * 4]) = c;
        float v1b = c.x; int i1 = lane * 4;
        float v2b = -INFINITY; int i2 = 0;
        {
            float vals[3] = {c.y, c.z, c.w};
            #pragma unroll
            for (int j = 0; j < 3; ++j) {
                float val = vals[j]; int idx = lane * 4 + j + 1;
                if (val > v1b) { v2b = v1b; i2 = i1; v1b = val; i1 = idx; }
                else if (val > v2b) { v2b = val; i2 = idx; }
            }
        }
        #pragma unroll
        for (int o = 1; o < 64; o <<= 1) {
            float ov1 = __shfl_xor(v1b, o);
            float ov2 = __shfl_xor(v2b, o);
            int   oi1 = __shfl_xor(i1, o);
            int   oi2 = __shfl_xor(i2, o);
            if (ov1 > v1b || (ov1 == v1b && oi1 < i1)) {
                float nv2; int ni2;
                if (v1b > ov2 || (v1b == ov2 && i1 < oi2)) { nv2 = v1b; ni2 = i1; }
                else { nv2 = ov2; ni2 = oi2; }
                v1b = ov1; i1 = oi1; v2b = nv2; i2 = ni2;
            } else if (ov1 > v2b || (ov1 == v2b && oi1 < i2)) {
                v2b = ov1; i2 = oi1;
            }
        }
        if (lane == 0) {
            out_dpidx[row] = (float)i1;
            out_hnidx[row] = (float)i2;
            out_top1[row]  = v2b;
            ws_dpidx[row]  = i1;
            ws_hnidx[row]  = i2;
        }
    }
}

// ---------------------------------------------------------------------------
// Kernel 3 (kwrite): ALL bulk writes (100 MB). Launched 3x THIS ROUND as a
// duration probe (idempotent). grid = B_N + 1088 blocks x 256 threads.
// ---------------------------------------------------------------------------
__global__ __launch_bounds__(256) void kwrite_kernel(
    const float* __restrict__ cent,
    const int* __restrict__ dpidx, const int* __restrict__ hnidx,
    float* __restrict__ out_dpcent, float* __restrict__ out_hneg,
    float* __restrict__ out_cluster, float* __restrict__ out_indexdp)
{
    int bid = blockIdx.x;
    int tid = threadIdx.x;
    if (bid < B_N) {
        int b = bid;
        int i1 = dpidx[b], i2 = hnidx[b];
        float4 v1 = reinterpret_cast<const float4*>(cent + (size_t)i1 * D_N)[tid];
        float4 v2 = reinterpret_cast<const float4*>(cent + (size_t)i2 * D_N)[tid];
        reinterpret_cast<float4*>(out_dpcent + (size_t)b * D_N)[tid] = v1;
        reinterpret_cast<float4*>(out_hneg   + (size_t)b * D_N)[tid] = v2;
        return;
    }
    int cb   = bid - B_N;          // 0..1087
    int base = cb * 4;
    const int4* dpi4 = reinterpret_cast<const int4*>(dpidx);
    int4 ixq[4];
    #pragma unroll
    for (int q = 0; q < 4; ++q) ixq[q] = dpi4[q * 256 + tid];   // j = q*1024+tid*4

    if (base < B_N) {
        int4 me4 = dpi4[cb];           // dpidx[base .. base+3]
        int mes[4] = {me4.x, me4.y, me4.z, me4.w};
        #pragma unroll
        for (int r = 0; r < 4; ++r) {
            int gr = base + r;
            int me = mes[r];
            float* dst = out_cluster + (size_t)gr * B_N;
            #pragma unroll
            for (int q = 0; q < 4; ++q) {
                int j = q * 1024 + tid * 4;
                float4 v;
                v.x = (ixq[q].x == me && (j + 0) != gr) ? 1.0f : 0.0f;
                v.y = (ixq[q].y == me && (j + 1) != gr) ? 1.0f : 0.0f;
                v.z = (ixq[q].z == me && (j + 2) != gr) ? 1.0f : 0.0f;
                v.w = (ixq[q].w == me && (j + 3) != gr) ? 1.0f : 0.0f;
                *reinterpret_cast<float4*>(dst + j) = v;
            }
        }
    } else {
        #pragma unroll
        for (int r = 0; r < 4; ++r) {
            int k = base + r - B_N;
            float* dst = out_indexdp + (size_t)k * B_N;
            #pragma unroll
            for (int q = 0; q < 4; ++q) {
                int j = q * 1024 + tid * 4;
                float4 v;
                v.x = (ixq[q].x == k) ? 1.0f : 0.0f;
                v.y = (ixq[q].y == k) ? 1.0f : 0.0f;
                v.z = (ixq[q].z == k) ? 1.0f : 0.0f;
                v.w = (ixq[q].w == k) ? 1.0f : 0.0f;
                *reinterpret_cast<float4*>(dst + j) = v;
            }
        }
    }
}

extern "C" void kernel_launch(void* const* d_in, const int* in_sizes, int n_in,
                              void* d_out, int out_size, void* d_ws, size_t ws_size,
                              hipStream_t stream)
{
    const float* dp   = (const float*)d_in[0];   // 4096 x 1024 f32
    const float* cent = (const float*)d_in[1];   // 256 x 1024 f32
    // d_in[2] (batch_cos_sim) is unused by the reference outputs.
    float* out = (float*)d_out;

    float* o_sims   = out;                 // 4096*256
    float* o_dpidx  = out + 1048576;       // 4096
    float* o_clust  = out + 1052672;       // 4096*4096
    float* o_idxdp  = out + 17829888;      // 256*4096
    float* o_dpcent = out + 18878464;      // 4096*1024
    float* o_hneg   = out + 23072768;      // 4096*1024
    float* o_hnidx  = out + 27267072;      // 4096
    float* o_top1   = out + 27271168;      // 4096

    char* ws = (char*)d_ws;
    ushort* phi  = (ushort*)ws;                         // 512 KiB packed hi
    ushort* plo  = (ushort*)(ws + (512u << 10));        // 512 KiB packed lo
    int*    widx = (int*)(ws + (1u << 20));             // 16 KiB
    int*    whn  = (int*)(ws + (1u << 20) + 16384);     // 16 KiB

    hipLaunchKernelGGL(kcent_kernel, dim3(K_N), dim3(256), 0, stream,
                       cent, phi, plo);
    hipLaunchKernelGGL(kmain_kernel, dim3(B_N / 16), dim3(1024), 0, stream,
                       dp, phi, plo,
                       o_sims, o_dpidx, o_hnidx, o_top1, widx, whn);
    // MEASUREMENT: kwrite x3 (idempotent). T24 - T23 = 2*(kwrite + gap).
    hipLaunchKernelGGL(kwrite_kernel, dim3(B_N + 1088), dim3(256), 0, stream,
                       cent, widx, whn,
                       o_dpcent, o_hneg, o_clust, o_idxdp);
    hipLaunchKernelGGL(kwrite_kernel, dim3(B_N + 1088), dim3(256), 0, stream,
                       cent, widx, whn,
                       o_dpcent, o_hneg, o_clust, o_idxdp);
    hipLaunchKernelGGL(kwrite_kernel, dim3(B_N + 1088), dim3(256), 0, stream,
                       cent, widx, whn,
                       o_dpcent, o_hneg, o_clust, o_idxdp);
}

// Round 25
// 45.897 us; speedup vs baseline: 1.6944x; 1.6944x over previous
//
#include <hip/hip_runtime.h>
#include <hip/hip_bf16.h>
#include <math.h>

#define B_N 4096
#define D_N 1024
#define K_N 256
#define NSTEP 32

typedef __attribute__((ext_vector_type(8))) short bf16x8;           // 4 VGPR
typedef __attribute__((ext_vector_type(8))) unsigned short u16x8;   // 4 VGPR
typedef __attribute__((ext_vector_type(4))) float f32x4;            // MFMA C/D

static constexpr float K_EPS = 1e-8f;

static __device__ __forceinline__ unsigned short f32_to_bf16_rne(float f) {
    unsigned x = __builtin_bit_cast(unsigned, f);
    unsigned r = (x + 0x7FFFu + ((x >> 16) & 1u)) >> 16;
    return (unsigned short)r;
}
static __device__ __forceinline__ float bf16_bits_to_f32(unsigned short h) {
    unsigned x = ((unsigned)h) << 16;
    return __builtin_bit_cast(float, x);
}
static __device__ __forceinline__ void cvt8(
    float e0, float e1, float e2, float e3,
    float e4, float e5, float e6, float e7, u16x8& hv, u16x8& lv)
{
    ushort h0=f32_to_bf16_rne(e0), h1=f32_to_bf16_rne(e1),
           h2=f32_to_bf16_rne(e2), h3=f32_to_bf16_rne(e3),
           h4=f32_to_bf16_rne(e4), h5=f32_to_bf16_rne(e5),
           h6=f32_to_bf16_rne(e6), h7=f32_to_bf16_rne(e7);
    hv = (u16x8){h0,h1,h2,h3,h4,h5,h6,h7};
    lv = (u16x8){f32_to_bf16_rne(e0 - bf16_bits_to_f32(h0)),
                 f32_to_bf16_rne(e1 - bf16_bits_to_f32(h1)),
                 f32_to_bf16_rne(e2 - bf16_bits_to_f32(h2)),
                 f32_to_bf16_rne(e3 - bf16_bits_to_f32(h3)),
                 f32_to_bf16_rne(e4 - bf16_bits_to_f32(h4)),
                 f32_to_bf16_rne(e5 - bf16_bits_to_f32(h5)),
                 f32_to_bf16_rne(e6 - bf16_bits_to_f32(h6)),
                 f32_to_bf16_rne(e7 - bf16_bits_to_f32(h7))};
}

// ---------------------------------------------------------------------------
// Kernel 1: centroid normalize + bf16 hi/lo split into PACKED MFMA-fragment
// layout (R12-verified). FULL hi+lo (lo is load-bearing for argmax — R22).
// ---------------------------------------------------------------------------
__global__ __launch_bounds__(256) void kcent_kernel(
    const float* __restrict__ cent,
    ushort* __restrict__ phi, ushort* __restrict__ plo)
{
    int n   = blockIdx.x;
    int tid = threadIdx.x;
    float4 v = reinterpret_cast<const float4*>(cent + (size_t)n * D_N)[tid];
    float s = v.x * v.x + v.y * v.y + v.z * v.z + v.w * v.w;
    #pragma unroll
    for (int o = 32; o > 0; o >>= 1) s += __shfl_down(s, o);
    __shared__ float red[4];
    __shared__ float s_inv;
    if ((tid & 63) == 0) red[tid >> 6] = s;
    __syncthreads();
    if (tid == 0) {
        float t = red[0] + red[1] + red[2] + red[3];
        s_inv = 1.0f / fmaxf(sqrtf(t), K_EPS);
    }
    __syncthreads();
    float inv = s_inv;
    float e[4] = {v.x * inv, v.y * inv, v.z * inv, v.w * inv};
    ushort h4[4], l4[4];
    #pragma unroll
    for (int j = 0; j < 4; ++j) {
        ushort h = f32_to_bf16_rne(e[j]);
        float lo = e[j] - bf16_bits_to_f32(h);
        h4[j] = h;
        l4[j] = f32_to_bf16_rne(lo);
    }
    int nt = n >> 4, lr = n & 15;
    int k8 = tid >> 1, half = tid & 1;
    int t  = k8 >> 2, lg = k8 & 3;
    size_t chunk = (size_t)(nt * 32 + t) * 64 + lg * 16 + lr;
    *reinterpret_cast<ushort4*>(phi + chunk * 8 + half * 4) =
        make_ushort4(h4[0], h4[1], h4[2], h4[3]);
    *reinterpret_cast<ushort4*>(plo + chunk * 8 + half * 4) =
        make_ushort4(l4[0], l4[1], l4[2], l4[3]);
}

// ---------------------------------------------------------------------------
// Kernel 2 (main): R21-exact (best measured config: 44.03 us total).
// 256 blocks x 1024 threads (16 waves, 4/SIMD); 3-MFMA split product;
// depth-8 packed-B rotation; fused dp-normalize; fused top-2 + cent gathers.
// ---------------------------------------------------------------------------
__global__ __launch_bounds__(1024) void kmain_kernel(
    const float* __restrict__ dp, const float* __restrict__ cent,
    const ushort* __restrict__ phi, const ushort* __restrict__ plo,
    float* __restrict__ out_sims, float* __restrict__ out_dpidx,
    float* __restrict__ out_hnidx, float* __restrict__ out_top1,
    float* __restrict__ out_dpcent, float* __restrict__ out_hneg,
    int* __restrict__ ws_dpidx)
{
    __shared__ ushort AhL[16 * 1024];   // 32 KB (swizzled)
    __shared__ ushort AlL[16 * 1024];   // 32 KB
    __shared__ float  simsL[16 * 256];  // 16 KB
    int tid  = threadIdx.x;
    int lane = tid & 63;
    int w    = tid >> 6;        // wave 0..15
    int lr   = lane & 15;
    int lg   = lane >> 4;
    int brow = blockIdx.x * 16;

    const ushort* bh = phi + (size_t)w * 32 * 512 + (size_t)lane * 8;
    const ushort* bl = plo + (size_t)w * 32 * 512 + (size_t)lane * 8;

    #define LBF(t, H, L)                                                  \
        H = *reinterpret_cast<const bf16x8*>(bh + (size_t)(t) * 512);     \
        L = *reinterpret_cast<const bf16x8*>(bl + (size_t)(t) * 512);

    bf16x8 h0,l0,h1,l1,h2,l2,h3,l3,h4,l4,h5,l5,h6,l6,h7,l7;
    LBF(0,h0,l0) LBF(1,h1,l1) LBF(2,h2,l2) LBF(3,h3,l3)
    LBF(4,h4,l4) LBF(5,h5,l5) LBF(6,h6,l6) LBF(7,h7,l7)

    {
        const float4* r4 = reinterpret_cast<const float4*>(
            dp + (size_t)(brow + w) * D_N);
        float4 a0 = r4[lane*4+0], a1 = r4[lane*4+1],
               a2 = r4[lane*4+2], a3 = r4[lane*4+3];
        float s = a0.x*a0.x + a0.y*a0.y + a0.z*a0.z + a0.w*a0.w
                + a1.x*a1.x + a1.y*a1.y + a1.z*a1.z + a1.w*a1.w
                + a2.x*a2.x + a2.y*a2.y + a2.z*a2.z + a2.w*a2.w
                + a3.x*a3.x + a3.y*a3.y + a3.z*a3.z + a3.w*a3.w;
        #pragma unroll
        for (int o = 1; o < 64; o <<= 1) s += __shfl_xor(s, o);
        float inv = 1.0f / fmaxf(sqrtf(s), K_EPS);
        u16x8 hv, lv;
        cvt8(a0.x*inv, a0.y*inv, a0.z*inv, a0.w*inv,
             a1.x*inv, a1.y*inv, a1.z*inv, a1.w*inv, hv, lv);
        int slot = (lane*2 + 0) ^ (w & 7);
        *reinterpret_cast<u16x8*>(&AhL[w*1024 + slot*8]) = hv;
        *reinterpret_cast<u16x8*>(&AlL[w*1024 + slot*8]) = lv;
        cvt8(a2.x*inv, a2.y*inv, a2.z*inv, a2.w*inv,
             a3.x*inv, a3.y*inv, a3.z*inv, a3.w*inv, hv, lv);
        slot = (lane*2 + 1) ^ (w & 7);
        *reinterpret_cast<u16x8*>(&AhL[w*1024 + slot*8]) = hv;
        *reinterpret_cast<u16x8*>(&AlL[w*1024 + slot*8]) = lv;
    }
    __syncthreads();

    f32x4 acc = {};
    const char* AhC = (const char*)AhL;
    const char* AlC = (const char*)AlL;
    auto step = [&](int t, bf16x8 hb, bf16x8 lb) {
        unsigned ca = (unsigned)((4*t + lg) ^ (lr & 7));
        unsigned ao = (unsigned)lr * 2048u + ca * 16u;
        bf16x8 ah = *reinterpret_cast<const bf16x8*>(AhC + ao);
        bf16x8 al = *reinterpret_cast<const bf16x8*>(AlC + ao);
        acc = __builtin_amdgcn_mfma_f32_16x16x32_bf16(ah, hb, acc, 0, 0, 0);
        acc = __builtin_amdgcn_mfma_f32_16x16x32_bf16(ah, lb, acc, 0, 0, 0);
        acc = __builtin_amdgcn_mfma_f32_16x16x32_bf16(al, hb, acc, 0, 0, 0);
    };
    #pragma unroll 1
    for (int t = 0; t < NSTEP; t += 8) {
        step(t + 0, h0, l0); if (t +  8 < NSTEP) { LBF(t +  8, h0, l0) }
        step(t + 1, h1, l1); if (t +  9 < NSTEP) { LBF(t +  9, h1, l1) }
        step(t + 2, h2, l2); if (t + 10 < NSTEP) { LBF(t + 10, h2, l2) }
        step(t + 3, h3, l3); if (t + 11 < NSTEP) { LBF(t + 11, h3, l3) }
        step(t + 4, h4, l4); if (t + 12 < NSTEP) { LBF(t + 12, h4, l4) }
        step(t + 5, h5, l5); if (t + 13 < NSTEP) { LBF(t + 13, h5, l5) }
        step(t + 6, h6, l6); if (t + 14 < NSTEP) { LBF(t + 14, h6, l6) }
        step(t + 7, h7, l7); if (t + 15 < NSTEP) { LBF(t + 15, h7, l7) }
    }
    #undef LBF

    // D layout: col = lane&15, row = (lane>>4)*4 + reg (m89-verified)
    #pragma unroll
    for (int r = 0; r < 4; ++r)
        simsL[(lg*4 + r) * K_N + w*16 + lr] = acc[r];
    __syncthreads();

    {
        float4 c = *reinterpret_cast<const float4*>(&simsL[w * K_N + lane * 4]);
        int row = brow + w;
        *reinterpret_cast<float4*>(&out_sims[(size_t)row * K_N + lane * 4]) = c;
        float v1b = c.x; int i1 = lane * 4;
        float v2b = -INFINITY; int i2 = 0;
        {
            float vals[3] = {c.y, c.z, c.w};
            #pragma unroll
            for (int j = 0; j < 3; ++j) {
                float val = vals[j]; int idx = lane * 4 + j + 1;
                if (val > v1b) { v2b = v1b; i2 = i1; v1b = val; i1 = idx; }
                else if (val > v2b) { v2b = val; i2 = idx; }
            }
        }
        #pragma unroll
        for (int o = 1; o < 64; o <<= 1) {
            float ov1 = __shfl_xor(v1b, o);
            float ov2 = __shfl_xor(v2b, o);
            int   oi1 = __shfl_xor(i1, o);
            int   oi2 = __shfl_xor(i2, o);
            if (ov1 > v1b || (ov1 == v1b && oi1 < i1)) {
                float nv2; int ni2;
                if (v1b > ov2 || (v1b == ov2 && i1 < oi2)) { nv2 = v1b; ni2 = i1; }
                else { nv2 = ov2; ni2 = oi2; }
                v1b = ov1; i1 = oi1; v2b = nv2; i2 = ni2;
            } else if (ov1 > v2b || (ov1 == v2b && oi1 < i2)) {
                v2b = ov1; i2 = oi1;
            }
        }
        const float4* cent4 = reinterpret_cast<const float4*>(cent);
        #pragma unroll
        for (int q = 0; q < 4; ++q) {
            float4 g1 = cent4[(size_t)i1 * 256 + q * 64 + lane];
            float4 g2 = cent4[(size_t)i2 * 256 + q * 64 + lane];
            reinterpret_cast<float4*>(out_dpcent + (size_t)row * D_N)[q*64 + lane] = g1;
            reinterpret_cast<float4*>(out_hneg   + (size_t)row * D_N)[q*64 + lane] = g2;
        }
        if (lane == 0) {
            out_dpidx[row] = (float)i1;
            out_hnidx[row] = (float)i2;
            out_top1[row]  = v2b;
            ws_dpidx[row]  = i1;
        }
    }
}

// ---------------------------------------------------------------------------
// Kernel 3: dp_cluster + index_dp, 16 rows/block (4 row-quads x 4 waves-group)
// grid = 272 blocks x 1024 threads — 4x fewer blocks than R21 (launch ramp).
// Sub-group sb = tid>>8 handles row-quad group = bid*4 + sb (R21-verified
// inner code). Branch is uniform per sub-group (group<1024 <=> cluster).
// ---------------------------------------------------------------------------
__global__ __launch_bounds__(1024) void kclust_kernel(
    const int* __restrict__ dpidx,
    float* __restrict__ out_cluster, float* __restrict__ out_indexdp)
{
    int tid = threadIdx.x;
    int sb  = tid >> 8;            // 0..3
    int t   = tid & 255;           // 0..255
    int grp = blockIdx.x * 4 + sb; // 0..1087
    int base = grp * 4;
    const int4* dpi4 = reinterpret_cast<const int4*>(dpidx);

    int4 ixq[4];
    #pragma unroll
    for (int q = 0; q < 4; ++q) ixq[q] = dpi4[q * 256 + t];   // j = q*1024+t*4

    if (base < B_N) {
        int4 me4 = dpi4[grp];          // dpidx[base .. base+3]
        int mes[4] = {me4.x, me4.y, me4.z, me4.w};
        #pragma unroll
        for (int r = 0; r < 4; ++r) {
            int gr = base + r;
            int me = mes[r];
            float* dst = out_cluster + (size_t)gr * B_N;
            #pragma unroll
            for (int q = 0; q < 4; ++q) {
                int j = q * 1024 + t * 4;
                float4 v;
                v.x = (ixq[q].x == me && (j + 0) != gr) ? 1.0f : 0.0f;
                v.y = (ixq[q].y == me && (j + 1) != gr) ? 1.0f : 0.0f;
                v.z = (ixq[q].z == me && (j + 2) != gr) ? 1.0f : 0.0f;
                v.w = (ixq[q].w == me && (j + 3) != gr) ? 1.0f : 0.0f;
                *reinterpret_cast<float4*>(dst + j) = v;
            }
        }
    } else {
        #pragma unroll
        for (int r = 0; r < 4; ++r) {
            int k = base + r - B_N;
            float* dst = out_indexdp + (size_t)k * B_N;
            #pragma unroll
            for (int q = 0; q < 4; ++q) {
                int j = q * 1024 + t * 4;
                float4 v;
                v.x = (ixq[q].x == k) ? 1.0f : 0.0f;
                v.y = (ixq[q].y == k) ? 1.0f : 0.0f;
                v.z = (ixq[q].z == k) ? 1.0f : 0.0f;
                v.w = (ixq[q].w == k) ? 1.0f : 0.0f;
                *reinterpret_cast<float4*>(dst + j) = v;
            }
        }
    }
}

extern "C" void kernel_launch(void* const* d_in, const int* in_sizes, int n_in,
                              void* d_out, int out_size, void* d_ws, size_t ws_size,
                              hipStream_t stream)
{
    const float* dp   = (const float*)d_in[0];   // 4096 x 1024 f32
    const float* cent = (const float*)d_in[1];   // 256 x 1024 f32
    // d_in[2] (batch_cos_sim) is unused by the reference outputs.
    float* out = (float*)d_out;

    float* o_sims   = out;                 // 4096*256
    float* o_dpidx  = out + 1048576;       // 4096
    float* o_clust  = out + 1052672;       // 4096*4096
    float* o_idxdp  = out + 17829888;      // 256*4096
    float* o_dpcent = out + 18878464;      // 4096*1024
    float* o_hneg   = out + 23072768;      // 4096*1024
    float* o_hnidx  = out + 27267072;      // 4096
    float* o_top1   = out + 27271168;      // 4096

    char* ws = (char*)d_ws;
    ushort* phi  = (ushort*)ws;                         // 512 KiB packed hi
    ushort* plo  = (ushort*)(ws + (512u << 10));        // 512 KiB packed lo
    int*    widx = (int*)(ws + (1u << 20));             // 16 KiB

    hipLaunchKernelGGL(kcent_kernel, dim3(K_N), dim3(256), 0, stream,
                       cent, phi, plo);
    hipLaunchKernelGGL(kmain_kernel, dim3(B_N / 16), dim3(1024), 0, stream,
                       dp, cent, phi, plo,
                       o_sims, o_dpidx, o_hnidx, o_top1,
                       o_dpcent, o_hneg, widx);
    hipLaunchKernelGGL(kclust_kernel, dim3((B_N + 256) / 16), dim3(1024), 0, stream,
                       widx, o_clust, o_idxdp);
}

// Round 26
// 43.587 us; speedup vs baseline: 1.7842x; 1.0530x over previous
//
#include <hip/hip_runtime.h>
#include <hip/hip_bf16.h>
#include <math.h>

#define B_N 4096
#define D_N 1024
#define K_N 256
#define NSTEP 32

typedef __attribute__((ext_vector_type(8))) short bf16x8;           // 4 VGPR
typedef __attribute__((ext_vector_type(8))) unsigned short u16x8;   // 4 VGPR
typedef __attribute__((ext_vector_type(4))) float f32x4;            // MFMA C/D

static constexpr float K_EPS = 1e-8f;

static __device__ __forceinline__ unsigned short f32_to_bf16_rne(float f) {
    unsigned x = __builtin_bit_cast(unsigned, f);
    unsigned r = (x + 0x7FFFu + ((x >> 16) & 1u)) >> 16;
    return (unsigned short)r;
}
static __device__ __forceinline__ float bf16_bits_to_f32(unsigned short h) {
    unsigned x = ((unsigned)h) << 16;
    return __builtin_bit_cast(float, x);
}
static __device__ __forceinline__ void cvt8(
    float e0, float e1, float e2, float e3,
    float e4, float e5, float e6, float e7, u16x8& hv, u16x8& lv)
{
    ushort h0=f32_to_bf16_rne(e0), h1=f32_to_bf16_rne(e1),
           h2=f32_to_bf16_rne(e2), h3=f32_to_bf16_rne(e3),
           h4=f32_to_bf16_rne(e4), h5=f32_to_bf16_rne(e5),
           h6=f32_to_bf16_rne(e6), h7=f32_to_bf16_rne(e7);
    hv = (u16x8){h0,h1,h2,h3,h4,h5,h6,h7};
    lv = (u16x8){f32_to_bf16_rne(e0 - bf16_bits_to_f32(h0)),
                 f32_to_bf16_rne(e1 - bf16_bits_to_f32(h1)),
                 f32_to_bf16_rne(e2 - bf16_bits_to_f32(h2)),
                 f32_to_bf16_rne(e3 - bf16_bits_to_f32(h3)),
                 f32_to_bf16_rne(e4 - bf16_bits_to_f32(h4)),
                 f32_to_bf16_rne(e5 - bf16_bits_to_f32(h5)),
                 f32_to_bf16_rne(e6 - bf16_bits_to_f32(h6)),
                 f32_to_bf16_rne(e7 - bf16_bits_to_f32(h7))};
}

// ---------------------------------------------------------------------------
// Kernel 1: centroid normalize + bf16 hi/lo split into PACKED MFMA-fragment
// layout (R12-verified). FULL hi+lo (lo is load-bearing for argmax — R22).
// ---------------------------------------------------------------------------
__global__ __launch_bounds__(256) void kcent_kernel(
    const float* __restrict__ cent,
    ushort* __restrict__ phi, ushort* __restrict__ plo)
{
    int n   = blockIdx.x;
    int tid = threadIdx.x;
    float4 v = reinterpret_cast<const float4*>(cent + (size_t)n * D_N)[tid];
    float s = v.x * v.x + v.y * v.y + v.z * v.z + v.w * v.w;
    #pragma unroll
    for (int o = 32; o > 0; o >>= 1) s += __shfl_down(s, o);
    __shared__ float red[4];
    __shared__ float s_inv;
    if ((tid & 63) == 0) red[tid >> 6] = s;
    __syncthreads();
    if (tid == 0) {
        float t = red[0] + red[1] + red[2] + red[3];
        s_inv = 1.0f / fmaxf(sqrtf(t), K_EPS);
    }
    __syncthreads();
    float inv = s_inv;
    float e[4] = {v.x * inv, v.y * inv, v.z * inv, v.w * inv};
    ushort h4[4], l4[4];
    #pragma unroll
    for (int j = 0; j < 4; ++j) {
        ushort h = f32_to_bf16_rne(e[j]);
        float lo = e[j] - bf16_bits_to_f32(h);
        h4[j] = h;
        l4[j] = f32_to_bf16_rne(lo);
    }
    int nt = n >> 4, lr = n & 15;
    int k8 = tid >> 1, half = tid & 1;
    int t  = k8 >> 2, lg = k8 & 3;
    size_t chunk = (size_t)(nt * 32 + t) * 64 + lg * 16 + lr;
    *reinterpret_cast<ushort4*>(phi + chunk * 8 + half * 4) =
        make_ushort4(h4[0], h4[1], h4[2], h4[3]);
    *reinterpret_cast<ushort4*>(plo + chunk * 8 + half * 4) =
        make_ushort4(l4[0], l4[1], l4[2], l4[3]);
}

// ---------------------------------------------------------------------------
// Kernel 2 (main): fused dp-normalize + split-MFMA GEMM + top-2 + gathers.
// 256 blocks x 1024 threads (16 waves, 4/SIMD); 3-MFMA split product;
// depth-8 packed-B register rotation (contiguous 1KB wave-loads); XOR-
// swizzled A-tiles in LDS; fused top-2 butterfly + cent gathers.
// ---------------------------------------------------------------------------
__global__ __launch_bounds__(1024) void kmain_kernel(
    const float* __restrict__ dp, const float* __restrict__ cent,
    const ushort* __restrict__ phi, const ushort* __restrict__ plo,
    float* __restrict__ out_sims, float* __restrict__ out_dpidx,
    float* __restrict__ out_hnidx, float* __restrict__ out_top1,
    float* __restrict__ out_dpcent, float* __restrict__ out_hneg,
    int* __restrict__ ws_dpidx)
{
    __shared__ ushort AhL[16 * 1024];   // 32 KB (swizzled)
    __shared__ ushort AlL[16 * 1024];   // 32 KB
    __shared__ float  simsL[16 * 256];  // 16 KB
    int tid  = threadIdx.x;
    int lane = tid & 63;
    int w    = tid >> 6;        // wave 0..15
    int lr   = lane & 15;
    int lg   = lane >> 4;
    int brow = blockIdx.x * 16;

    const ushort* bh = phi + (size_t)w * 32 * 512 + (size_t)lane * 8;
    const ushort* bl = plo + (size_t)w * 32 * 512 + (size_t)lane * 8;

    #define LBF(t, H, L)                                                  \
        H = *reinterpret_cast<const bf16x8*>(bh + (size_t)(t) * 512);     \
        L = *reinterpret_cast<const bf16x8*>(bl + (size_t)(t) * 512);

    bf16x8 h0,l0,h1,l1,h2,l2,h3,l3,h4,l4,h5,l5,h6,l6,h7,l7;
    LBF(0,h0,l0) LBF(1,h1,l1) LBF(2,h2,l2) LBF(3,h3,l3)
    LBF(4,h4,l4) LBF(5,h5,l5) LBF(6,h6,l6) LBF(7,h7,l7)

    {
        const float4* r4 = reinterpret_cast<const float4*>(
            dp + (size_t)(brow + w) * D_N);
        float4 a0 = r4[lane*4+0], a1 = r4[lane*4+1],
               a2 = r4[lane*4+2], a3 = r4[lane*4+3];
        float s = a0.x*a0.x + a0.y*a0.y + a0.z*a0.z + a0.w*a0.w
                + a1.x*a1.x + a1.y*a1.y + a1.z*a1.z + a1.w*a1.w
                + a2.x*a2.x + a2.y*a2.y + a2.z*a2.z + a2.w*a2.w
                + a3.x*a3.x + a3.y*a3.y + a3.z*a3.z + a3.w*a3.w;
        #pragma unroll
        for (int o = 1; o < 64; o <<= 1) s += __shfl_xor(s, o);
        float inv = 1.0f / fmaxf(sqrtf(s), K_EPS);
        u16x8 hv, lv;
        cvt8(a0.x*inv, a0.y*inv, a0.z*inv, a0.w*inv,
             a1.x*inv, a1.y*inv, a1.z*inv, a1.w*inv, hv, lv);
        int slot = (lane*2 + 0) ^ (w & 7);
        *reinterpret_cast<u16x8*>(&AhL[w*1024 + slot*8]) = hv;
        *reinterpret_cast<u16x8*>(&AlL[w*1024 + slot*8]) = lv;
        cvt8(a2.x*inv, a2.y*inv, a2.z*inv, a2.w*inv,
             a3.x*inv, a3.y*inv, a3.z*inv, a3.w*inv, hv, lv);
        slot = (lane*2 + 1) ^ (w & 7);
        *reinterpret_cast<u16x8*>(&AhL[w*1024 + slot*8]) = hv;
        *reinterpret_cast<u16x8*>(&AlL[w*1024 + slot*8]) = lv;
    }
    __syncthreads();

    f32x4 acc = {};
    const char* AhC = (const char*)AhL;
    const char* AlC = (const char*)AlL;
    auto step = [&](int t, bf16x8 hb, bf16x8 lb) {
        unsigned ca = (unsigned)((4*t + lg) ^ (lr & 7));
        unsigned ao = (unsigned)lr * 2048u + ca * 16u;
        bf16x8 ah = *reinterpret_cast<const bf16x8*>(AhC + ao);
        bf16x8 al = *reinterpret_cast<const bf16x8*>(AlC + ao);
        acc = __builtin_amdgcn_mfma_f32_16x16x32_bf16(ah, hb, acc, 0, 0, 0);
        acc = __builtin_amdgcn_mfma_f32_16x16x32_bf16(ah, lb, acc, 0, 0, 0);
        acc = __builtin_amdgcn_mfma_f32_16x16x32_bf16(al, hb, acc, 0, 0, 0);
    };
    #pragma unroll 1
    for (int t = 0; t < NSTEP; t += 8) {
        step(t + 0, h0, l0); if (t +  8 < NSTEP) { LBF(t +  8, h0, l0) }
        step(t + 1, h1, l1); if (t +  9 < NSTEP) { LBF(t +  9, h1, l1) }
        step(t + 2, h2, l2); if (t + 10 < NSTEP) { LBF(t + 10, h2, l2) }
        step(t + 3, h3, l3); if (t + 11 < NSTEP) { LBF(t + 11, h3, l3) }
        step(t + 4, h4, l4); if (t + 12 < NSTEP) { LBF(t + 12, h4, l4) }
        step(t + 5, h5, l5); if (t + 13 < NSTEP) { LBF(t + 13, h5, l5) }
        step(t + 6, h6, l6); if (t + 14 < NSTEP) { LBF(t + 14, h6, l6) }
        step(t + 7, h7, l7); if (t + 15 < NSTEP) { LBF(t + 15, h7, l7) }
    }
    #undef LBF

    // D layout: col = lane&15, row = (lane>>4)*4 + reg (m89-verified)
    #pragma unroll
    for (int r = 0; r < 4; ++r)
        simsL[(lg*4 + r) * K_N + w*16 + lr] = acc[r];
    __syncthreads();

    {
        float4 c = *reinterpret_cast<const float4*>(&simsL[w * K_N + lane * 4]);
        int row = brow + w;
        *reinterpret_cast<float4*>(&out_sims[(size_t)row * K_N + lane * 4]) = c;
        float v1b = c.x; int i1 = lane * 4;
        float v2b = -INFINITY; int i2 = 0;
        {
            float vals[3] = {c.y, c.z, c.w};
            #pragma unroll
            for (int j = 0; j < 3; ++j) {
                float val = vals[j]; int idx = lane * 4 + j + 1;
                if (val > v1b) { v2b = v1b; i2 = i1; v1b = val; i1 = idx; }
                else if (val > v2b) { v2b = val; i2 = idx; }
            }
        }
        #pragma unroll
        for (int o = 1; o < 64; o <<= 1) {
            float ov1 = __shfl_xor(v1b, o);
            float ov2 = __shfl_xor(v2b, o);
            int   oi1 = __shfl_xor(i1, o);
            int   oi2 = __shfl_xor(i2, o);
            if (ov1 > v1b || (ov1 == v1b && oi1 < i1)) {
                float nv2; int ni2;
                if (v1b > ov2 || (v1b == ov2 && i1 < oi2)) { nv2 = v1b; ni2 = i1; }
                else { nv2 = ov2; ni2 = oi2; }
                v1b = ov1; i1 = oi1; v2b = nv2; i2 = ni2;
            } else if (ov1 > v2b || (ov1 == v2b && oi1 < i2)) {
                v2b = ov1; i2 = oi1;
            }
        }
        const float4* cent4 = reinterpret_cast<const float4*>(cent);
        #pragma unroll
        for (int q = 0; q < 4; ++q) {
            float4 g1 = cent4[(size_t)i1 * 256 + q * 64 + lane];
            float4 g2 = cent4[(size_t)i2 * 256 + q * 64 + lane];
            reinterpret_cast<float4*>(out_dpcent + (size_t)row * D_N)[q*64 + lane] = g1;
            reinterpret_cast<float4*>(out_hneg   + (size_t)row * D_N)[q*64 + lane] = g2;
        }
        if (lane == 0) {
            out_dpidx[row] = (float)i1;
            out_hnidx[row] = (float)i2;
            out_top1[row]  = v2b;
            ws_dpidx[row]  = i1;
        }
    }
}

// ---------------------------------------------------------------------------
// Kernel 3: dp_cluster (B x B) + index_dp (K x B), BATCHED 4 rows/block
// (R21-verified best). grid = 1088 blocks x 256 threads.
// ---------------------------------------------------------------------------
__global__ __launch_bounds__(256) void kclust_kernel(
    const int* __restrict__ dpidx,
    float* __restrict__ out_cluster, float* __restrict__ out_indexdp)
{
    int bid  = blockIdx.x;
    int tid  = threadIdx.x;
    int base = bid * 4;
    const int4* dpi4 = reinterpret_cast<const int4*>(dpidx);

    int4 ixq[4];
    #pragma unroll
    for (int q = 0; q < 4; ++q) ixq[q] = dpi4[q * 256 + tid];   // j = q*1024+tid*4

    if (base < B_N) {
        int4 me4 = dpi4[bid];            // dpidx[base .. base+3]
        int mes[4] = {me4.x, me4.y, me4.z, me4.w};
        #pragma unroll
        for (int r = 0; r < 4; ++r) {
            int gr = base + r;
            int me = mes[r];
            float* dst = out_cluster + (size_t)gr * B_N;
            #pragma unroll
            for (int q = 0; q < 4; ++q) {
                int j = q * 1024 + tid * 4;
                float4 v;
                v.x = (ixq[q].x == me && (j + 0) != gr) ? 1.0f : 0.0f;
                v.y = (ixq[q].y == me && (j + 1) != gr) ? 1.0f : 0.0f;
                v.z = (ixq[q].z == me && (j + 2) != gr) ? 1.0f : 0.0f;
                v.w = (ixq[q].w == me && (j + 3) != gr) ? 1.0f : 0.0f;
                *reinterpret_cast<float4*>(dst + j) = v;
            }
        }
    } else {
        #pragma unroll
        for (int r = 0; r < 4; ++r) {
            int k = base + r - B_N;
            float* dst = out_indexdp + (size_t)k * B_N;
            #pragma unroll
            for (int q = 0; q < 4; ++q) {
                int j = q * 1024 + tid * 4;
                float4 v;
                v.x = (ixq[q].x == k) ? 1.0f : 0.0f;
                v.y = (ixq[q].y == k) ? 1.0f : 0.0f;
                v.z = (ixq[q].z == k) ? 1.0f : 0.0f;
                v.w = (ixq[q].w == k) ? 1.0f : 0.0f;
                *reinterpret_cast<float4*>(dst + j) = v;
            }
        }
    }
}

extern "C" void kernel_launch(void* const* d_in, const int* in_sizes, int n_in,
                              void* d_out, int out_size, void* d_ws, size_t ws_size,
                              hipStream_t stream)
{
    const float* dp   = (const float*)d_in[0];   // 4096 x 1024 f32
    const float* cent = (const float*)d_in[1];   // 256 x 1024 f32
    // d_in[2] (batch_cos_sim) is unused by the reference outputs.
    float* out = (float*)d_out;

    float* o_sims   = out;                 // 4096*256
    float* o_dpidx  = out + 1048576;       // 4096
    float* o_clust  = out + 1052672;       // 4096*4096
    float* o_idxdp  = out + 17829888;      // 256*4096
    float* o_dpcent = out + 18878464;      // 4096*1024
    float* o_hneg   = out + 23072768;      // 4096*1024
    float* o_hnidx  = out + 27267072;      // 4096
    float* o_top1   = out + 27271168;      // 4096

    char* ws = (char*)d_ws;
    ushort* phi  = (ushort*)ws;                         // 512 KiB packed hi
    ushort* plo  = (ushort*)(ws + (512u << 10));        // 512 KiB packed lo
    int*    widx = (int*)(ws + (1u << 20));             // 16 KiB

    hipLaunchKernelGGL(kcent_kernel, dim3(K_N), dim3(256), 0, stream,
                       cent, phi, plo);
    hipLaunchKernelGGL(kmain_kernel, dim3(B_N / 16), dim3(1024), 0, stream,
                       dp, cent, phi, plo,
                       o_sims, o_dpidx, o_hnidx, o_top1,
                       o_dpcent, o_hneg, widx);
    hipLaunchKernelGGL(kclust_kernel, dim3((B_N + K_N) / 4), dim3(256), 0, stream,
                       widx, o_clust, o_idxdp);
}